// Round 3
// baseline (350.197 us; speedup 1.0000x reference)
//
#include <hip/hip_runtime.h>

// features: (B=4, C=1024, 14, 14) fp32; H_Box/O_Box: (4,16,6); im_h=480, im_w=640
// Outputs (flat concat, fp32):
//   H_Node   (4,16,1024,7,7)      = 3,211,264   @ 0
//   O_Node   (4,16,1024,7,7)      = 3,211,264   @ 3,211,264
//   H_O_Node (4,16,16,1024,7,7)   = 51,380,224  @ 6,422,528
//   geometry (4,16,16,9)          = 9,216       @ 57,802,752
//   h_ratio  (4,16)               = 64          @ 57,811,968
//   o_ratio  (4,16)               = 64          @ 57,812,032
//   ho_ratio (4,16,16)            = 1,024       @ 57,812,096

#define C_CH   1024
#define HW     14
#define PLANE  196              // 14*14 floats per channel plane
#define OUTS   7
#define TILE   (C_CH * OUTS * OUTS)   // 50176 elems per roi
#define OFF_O  3211264
#define OFF_U  6422528
#define OFF_G  57802752
#define OFF_HR 57811968
#define OFF_OR 57812032
#define OFF_UR 57812096

// WRITE-DENSITY-FIRST decomposition. Previous channel-split wrote each roi's
// 200-KB tile as 64 uncorrelated 3-KB bursts (2048 chip-wide walkers) ->
// HBM row-miss-bound at ~2.3 TB/s effective (store-width and occupancy
// experiments both neutral -> drain-side, not issue-side). Now: one block =
// ONE roi; block loops 1024 channels in 32-ch LDS chunks and emits its tile
// as one dense sequential 200-KB stream (4 waves interleaved at 196 B).
// 1156 blocks, 25 KB LDS -> 6 blocks/CU, all resident. All blocks sweep
// channels in the same order -> per-XCD read band stays L2-hot.
#define CHUNK       32                  // channels staged per chunk
#define NCHUNK      (C_CH / CHUNK)      // 32 chunks
#define CH_PER_WAVE (CHUNK / 4)         // 8 channels per wave per chunk

__global__ __launch_bounds__(256, 6) void roi_align_kernel(
    const float* __restrict__ feat,
    const float* __restrict__ HBox,
    const float* __restrict__ OBox,
    const int* __restrict__ im_h_p,
    const int* __restrict__ im_w_p,
    float* __restrict__ out)
{
    __shared__ float lds[CHUNK * PLANE];    // 6272 floats = 25,088 B

    const float im_w = (float)(*im_w_p);
    const float im_h = (float)(*im_h_p);
    const int idx = blockIdx.x;

    // ---- merged pairwise-geometry blocks (idx 1152..1155) ----
    if (idx >= 1152) {
        const int p = (idx - 1152) * 256 + threadIdx.x;   // 0..1023
        const float im_area = im_h * im_w;

        const int b = p >> 8;
        const int h = (p >> 4) & 15;
        const int o = p & 15;
        const float* hb = HBox + (b * 16 + h) * 6;
        const float* ob = OBox + (b * 16 + o) * 6;
        const float hx1 = hb[0], hy1 = hb[1], hx2 = hb[2], hy2 = hb[3];
        const float ox1 = ob[0], oy1 = ob[1], ox2 = ob[2], oy2 = ob[3];

        const float h_cx = (hx1 + hx2) * 0.5f, h_cy = (hy1 + hy2) * 0.5f;
        const float h_w = hx2 - hx1, h_h = hy2 - hy1;
        const float o_cx = (ox1 + ox2) * 0.5f, o_cy = (oy1 + oy2) * 0.5f;
        const float o_w = ox2 - ox1, o_h = oy2 - oy1;

        const float dxc = h_cx - o_cx;
        const float dyc = h_cy - o_cy;
        const float adx = fabsf(dxc), ady = fabsf(dyc);

        const float d_x = adx / h_w * 100.0f;
        const float d_y = ady / h_h * 100.0f;
        const float d_xy = sqrtf(dxc * dxc + dyc * dyc) / (h_w + h_h) * 100.0f;
        const float dx_ratio = adx / im_w * 100.0f;
        const float dy_ratio = ady / im_h * 100.0f;
        const float det_y = (ady > 1e-5f) ? dyc : ((dyc > 0.0f) ? 1e-5f : -1e-5f);
        const float angle = atanf(dxc / det_y);
        const float area_scale = (o_w * o_h) / (h_w * h_h);
        const float o_scale = o_h / o_w;

        const float ix1 = fmaxf(hx1, ox1), iy1 = fmaxf(hy1, oy1);
        const float ix2 = fminf(hx2, ox2), iy2 = fminf(hy2, oy2);
        const float inter = fmaxf(ix2 - ix1, 0.0f) * fmaxf(iy2 - iy1, 0.0f);
        const float uni = h_w * h_h + o_w * o_h - inter;
        const float iou = (inter > 0.0f) ? inter / uni : 0.0f;

        float* g = out + OFF_G + (size_t)p * 9;
        g[0] = d_x; g[1] = d_y; g[2] = d_xy;
        g[3] = dx_ratio; g[4] = dy_ratio; g[5] = angle;
        g[6] = area_scale; g[7] = o_scale; g[8] = iou;

        const float ux1 = fminf(ox1, hx1), uy1 = fminf(oy1, hy1);
        const float ux2 = fmaxf(ox2, hx2), uy2 = fmaxf(oy2, hy2);
        out[OFF_UR + p] = (ux2 - ux1) * (uy2 - uy1) / im_area * 100.0f;

        if (p < 64) {
            const float* hb2 = HBox + p * 6;
            out[OFF_HR + p] = (hb2[2] - hb2[0]) * (hb2[3] - hb2[1]) / im_area * 100.0f;
            const float* ob2 = OBox + p * 6;
            out[OFF_OR + p] = (ob2[2] - ob2[0]) * (ob2[3] - ob2[1]) / im_area * 100.0f;
        }
        return;
    }

    // ---- roi block: idx -> (batch b, roi j within batch) ----
    const int b = idx / 288;
    const int j = idx - b * 288;

    float x1, y1, x2, y2;
    size_t outBase;
    if (j < 16) {
        const float* bx = HBox + (b * 16 + j) * 6;
        x1 = bx[0]; y1 = bx[1]; x2 = bx[2]; y2 = bx[3];
        outBase = (size_t)(b * 16 + j) * TILE;
    } else if (j < 32) {
        const float* bx = OBox + (b * 16 + (j - 16)) * 6;
        x1 = bx[0]; y1 = bx[1]; x2 = bx[2]; y2 = bx[3];
        outBase = OFF_O + (size_t)(b * 16 + (j - 16)) * TILE;
    } else {
        const int u = j - 32;
        const float* hb = HBox + (b * 16 + (u >> 4)) * 6;
        const float* ob = OBox + (b * 16 + (u & 15)) * 6;
        x1 = fminf(ob[0], hb[0]);
        y1 = fminf(ob[1], hb[1]);
        x2 = fmaxf(ob[2], hb[2]);
        y2 = fmaxf(ob[3], hb[3]);
        outBase = OFF_U + (size_t)(b * 256 + u) * TILE;
    }

    const int lane = threadIdx.x & 63;
    const int wave = threadIdx.x >> 6;
    const int pos = lane;                       // output position (49 active)
    const int oy = pos / 7;
    const int ox = pos - oy * 7;

    const float scx = (224.0f / im_w) * (1.0f / 16.0f);
    const float scy = (224.0f / im_h) * (1.0f / 16.0f);

    // bilinear descriptor (once per block, loop-invariant registers)
    const float bx1 = x1 * scx;
    const float by1 = y1 * scy;
    const float bw = (x2 * scx - bx1) * (1.0f / OUTS);
    const float bh = (y2 * scy - by1) * (1.0f / OUTS);
    float X = bx1 + ((float)ox + 0.5f) * bw;
    float Y = by1 + ((float)oy + 0.5f) * bh;
    X = fminf(fmaxf(X, 0.0f), (float)(HW - 1));
    Y = fminf(fmaxf(Y, 0.0f), (float)(HW - 1));
    // clamp base to <=12 so x1i=x0+1 always; X==13 -> lx=1 -> weight flows
    // to f01 which equals reference's clamped f00. Bit-equivalent result.
    // (lanes 49-63 compute clamped garbage; their reads stay in-bounds and
    //  their stores are predicated off.)
    const int x0 = min((int)floorf(X), HW - 2);
    const int y0 = min((int)floorf(Y), HW - 2);
    const float lx = X - (float)x0;
    const float ly = Y - (float)y0;
    const float w00 = (1.0f - ly) * (1.0f - lx);
    const float w01 = (1.0f - ly) * lx;
    const float w10 = ly * (1.0f - lx);
    const float w11 = ly * lx;
    const int off = y0 * HW + x0;

    const float* feat_b = feat + (size_t)b * C_CH * PLANE;
    float* outT = out + outBase;

    for (int ch = 0; ch < NCHUNK; ++ch) {
        // ---- stage 32 contiguous planes, fully coalesced float4 ----
        {
            const float4* g4 = (const float4*)(feat_b + (size_t)(ch * CHUNK) * PLANE);
            float4* l4 = (float4*)lds;
            for (int i = threadIdx.x; i < (CHUNK * PLANE / 4); i += 256)
                l4[i] = g4[i];
        }
        __syncthreads();

        // ---- compute: wave w owns channels {w, w+4, w+8, ...} of the chunk
        //      -> the 4 waves' 196-B stores interleave into one dense
        //      sequential stream over the roi tile ----
        if (lane < 49) {
            const float* lp = lds + wave * PLANE + off;
            float* op = outT + (size_t)(ch * CHUNK + wave) * 49 + pos;
#pragma unroll
            for (int kk = 0; kk < CH_PER_WAVE; ++kk) {
                // dword offsets {0,1,14,15} from per-channel base -> 2x ds_read2_b32
                const float f00 = lp[0];
                const float f01 = lp[1];
                const float f10 = lp[HW];
                const float f11 = lp[HW + 1];
                op[0] = f00 * w00 + f01 * w01 + f10 * w10 + f11 * w11;
                lp += 4 * PLANE;
                op += 4 * 49;
            }
        }
        __syncthreads();        // all taps read before next chunk overwrites
    }
}

extern "C" void kernel_launch(void* const* d_in, const int* in_sizes, int n_in,
                              void* d_out, int out_size, void* d_ws, size_t ws_size,
                              hipStream_t stream) {
    const float* feat = (const float*)d_in[0];
    const float* HBox = (const float*)d_in[1];
    const float* OBox = (const float*)d_in[2];
    const int* im_h = (const int*)d_in[3];
    const int* im_w = (const int*)d_in[4];
    float* out = (float*)d_out;

    // 1152 roi blocks (one per roi: 4 batches x 288) + 4 geometry blocks
    roi_align_kernel<<<1156, 256, 0, stream>>>(feat, HBox, OBox, im_h, im_w, out);
}

// Round 4
// 245.015 us; speedup vs baseline: 1.4293x; 1.4293x over previous
//
#include <hip/hip_runtime.h>

// features: (B=4, C=1024, 14, 14) fp32; H_Box/O_Box: (4,16,6); im_h=480, im_w=640
// Outputs (flat concat, fp32):
//   H_Node   (4,16,1024,7,7)      = 3,211,264   @ 0
//   O_Node   (4,16,1024,7,7)      = 3,211,264   @ 3,211,264
//   H_O_Node (4,16,16,1024,7,7)   = 51,380,224  @ 6,422,528
//   geometry (4,16,16,9)          = 9,216       @ 57,802,752
//   h_ratio  (4,16)               = 64          @ 57,811,968
//   o_ratio  (4,16)               = 64          @ 57,812,032
//   ho_ratio (4,16,16)            = 1,024       @ 57,812,096

#define C_CH   1024
#define HW     14
#define PLANE  196              // 14*14 floats per channel plane
#define OUTS   7
#define TILE   (C_CH * OUTS * OUTS)   // 50176 elems per roi
#define OFF_O  3211264
#define OFF_U  6422528
#define OFF_G  57802752
#define OFF_HR 57811968
#define OFF_OR 57812032
#define OFF_UR 57812096

#define CH_PER_BLK   32         // channels staged per block (25,088 B LDS)
#define CH_PER_WAVE  8          // 4 waves x 8 = 32
#define NSLOT        72         // concurrent roi slots; 72 x 16 steps = 1152 rois

// MOVING-WINDOW write order. Evidence (R3 counters): WRITE_SIZE == output
// size with FETCH ~0 -> L2 merges our stores into clean full-line writebacks;
// yet effective write drain is stuck at ~2.3 TB/s while the rocclr fill hits
// 6.6 TB/s on the same buffer. Difference: fill's grid-stride makes the whole
// chip write one ~2-4 MB band sweeping front-to-back (DRAM row locality);
// our concurrent roi tiles were spaced every 3.2 MB across the whole 231 MB.
// Fix: block = (roi-slot s, 32-channel group); step ri processes tile
// t = s + 72*ri  ->  all blocks at step ri write the CONTIGUOUS 14.4-MB band
// [72*ri*200KB, +14.4MB), sweeping the output in 16 steps. Feature planes are
// re-staged only when the tile's batch changes (~4-5x per block, L2-hot).
// Compute structure (taps via 2x ds_read2_b32, 196-B contiguous stores per
// wave-channel) is bit-identical to the proven R0 kernel.
__global__ __launch_bounds__(256) void roi_align_kernel(
    const float* __restrict__ feat,
    const float* __restrict__ HBox,
    const float* __restrict__ OBox,
    const int* __restrict__ im_h_p,
    const int* __restrict__ im_w_p,
    float* __restrict__ out)
{
    __shared__ float lds[CH_PER_BLK * PLANE];   // 6272 floats = 25,088 B

    const float im_w = (float)(*im_w_p);
    const float im_h = (float)(*im_h_p);

    // ---- merged pairwise-geometry blocks (x == 72, y < 4) ----
    if (blockIdx.x == NSLOT) {
        if (blockIdx.y >= 4) return;
        const int p = blockIdx.y * 256 + threadIdx.x;   // 0..1023
        const float im_area = im_h * im_w;

        const int b = p >> 8;
        const int h = (p >> 4) & 15;
        const int o = p & 15;
        const float* hb = HBox + (b * 16 + h) * 6;
        const float* ob = OBox + (b * 16 + o) * 6;
        const float hx1 = hb[0], hy1 = hb[1], hx2 = hb[2], hy2 = hb[3];
        const float ox1 = ob[0], oy1 = ob[1], ox2 = ob[2], oy2 = ob[3];

        const float h_cx = (hx1 + hx2) * 0.5f, h_cy = (hy1 + hy2) * 0.5f;
        const float h_w = hx2 - hx1, h_h = hy2 - hy1;
        const float o_cx = (ox1 + ox2) * 0.5f, o_cy = (oy1 + oy2) * 0.5f;
        const float o_w = ox2 - ox1, o_h = oy2 - oy1;

        const float dxc = h_cx - o_cx;
        const float dyc = h_cy - o_cy;
        const float adx = fabsf(dxc), ady = fabsf(dyc);

        const float d_x = adx / h_w * 100.0f;
        const float d_y = ady / h_h * 100.0f;
        const float d_xy = sqrtf(dxc * dxc + dyc * dyc) / (h_w + h_h) * 100.0f;
        const float dx_ratio = adx / im_w * 100.0f;
        const float dy_ratio = ady / im_h * 100.0f;
        const float det_y = (ady > 1e-5f) ? dyc : ((dyc > 0.0f) ? 1e-5f : -1e-5f);
        const float angle = atanf(dxc / det_y);
        const float area_scale = (o_w * o_h) / (h_w * h_h);
        const float o_scale = o_h / o_w;

        const float ix1 = fmaxf(hx1, ox1), iy1 = fmaxf(hy1, oy1);
        const float ix2 = fminf(hx2, ox2), iy2 = fminf(hy2, oy2);
        const float inter = fmaxf(ix2 - ix1, 0.0f) * fmaxf(iy2 - iy1, 0.0f);
        const float uni = h_w * h_h + o_w * o_h - inter;
        const float iou = (inter > 0.0f) ? inter / uni : 0.0f;

        float* g = out + OFF_G + (size_t)p * 9;
        g[0] = d_x; g[1] = d_y; g[2] = d_xy;
        g[3] = dx_ratio; g[4] = dy_ratio; g[5] = angle;
        g[6] = area_scale; g[7] = o_scale; g[8] = iou;

        const float ux1 = fminf(ox1, hx1), uy1 = fminf(oy1, hy1);
        const float ux2 = fmaxf(ox2, hx2), uy2 = fmaxf(oy2, hy2);
        out[OFF_UR + p] = (ux2 - ux1) * (uy2 - uy1) / im_area * 100.0f;

        if (p < 64) {
            const float* hb2 = HBox + p * 6;
            out[OFF_HR + p] = (hb2[2] - hb2[0]) * (hb2[3] - hb2[1]) / im_area * 100.0f;
            const float* ob2 = OBox + p * 6;
            out[OFF_OR + p] = (ob2[2] - ob2[0]) * (ob2[3] - ob2[1]) / im_area * 100.0f;
        }
        return;
    }

    const int slot = blockIdx.x;                // roi slot 0..71
    const int c0 = blockIdx.y * CH_PER_BLK;     // channel group

    const int lane = threadIdx.x & 63;
    const int wave = threadIdx.x >> 6;
    const int pos = lane;                       // output position (49 active)
    const int oy = pos / 7;
    const int ox = pos - oy * 7;

    const float scx = (224.0f / im_w) * (1.0f / 16.0f);
    const float scy = (224.0f / im_h) * (1.0f / 16.0f);

    const float* ldw = lds + (wave * CH_PER_WAVE) * PLANE;
    const int cw = c0 + wave * CH_PER_WAVE;     // first channel this wave owns

    int cur_b = -1;

    for (int ri = 0; ri < 16; ++ri) {
        const int t = slot + NSLOT * ri;        // global tile index, sweeping

        // decode tile -> (batch b, box geometry, output base)
        int b;
        float x1, y1, x2, y2;
        size_t outBase;
        if (t < 64) {
            b = t >> 4;
            const float* bx = HBox + t * 6;
            x1 = bx[0]; y1 = bx[1]; x2 = bx[2]; y2 = bx[3];
            outBase = (size_t)t * TILE;
        } else if (t < 128) {
            const int u = t - 64;
            b = u >> 4;
            const float* bx = OBox + u * 6;
            x1 = bx[0]; y1 = bx[1]; x2 = bx[2]; y2 = bx[3];
            outBase = OFF_O + (size_t)u * TILE;
        } else {
            const int u = t - 128;              // 0..1023
            b = u >> 8;
            const float* hb = HBox + (b * 16 + ((u >> 4) & 15)) * 6;
            const float* ob = OBox + (b * 16 + (u & 15)) * 6;
            x1 = fminf(ob[0], hb[0]);
            y1 = fminf(ob[1], hb[1]);
            x2 = fmaxf(ob[2], hb[2]);
            y2 = fmaxf(ob[3], hb[3]);
            outBase = OFF_U + (size_t)u * TILE;
        }

        // ---- (re)stage 32 contiguous planes of batch b when it changes ----
        if (b != cur_b) {
            __syncthreads();                    // all waves done with old planes
            const float4* g4 = (const float4*)(feat + ((size_t)b * C_CH + c0) * PLANE);
            float4* l4 = (float4*)lds;
            for (int i = threadIdx.x; i < (CH_PER_BLK * PLANE / 4); i += 256)
                l4[i] = g4[i];
            __syncthreads();
            cur_b = b;
        }

        if (lane < 49) {
            // bilinear descriptor (loop-invariant registers per step)
            const float bx1 = x1 * scx;
            const float by1 = y1 * scy;
            const float bw = (x2 * scx - bx1) * (1.0f / OUTS);
            const float bh = (y2 * scy - by1) * (1.0f / OUTS);
            float X = bx1 + ((float)ox + 0.5f) * bw;
            float Y = by1 + ((float)oy + 0.5f) * bh;
            X = fminf(fmaxf(X, 0.0f), (float)(HW - 1));
            Y = fminf(fmaxf(Y, 0.0f), (float)(HW - 1));
            // clamp base to <=12 so x1i=x0+1 always; X==13 -> lx=1 -> weight
            // flows to f01 which equals reference's clamped f00. Bit-equal.
            const int x0 = min((int)floorf(X), HW - 2);
            const int y0 = min((int)floorf(Y), HW - 2);
            const float lx = X - (float)x0;
            const float ly = Y - (float)y0;
            const float w00 = (1.0f - ly) * (1.0f - lx);
            const float w01 = (1.0f - ly) * lx;
            const float w10 = ly * (1.0f - lx);
            const float w11 = ly * lx;
            const int off = y0 * HW + x0;

            const float* lp = ldw + off;
            float* op = out + outBase + (size_t)cw * 49 + pos;
#pragma unroll
            for (int k = 0; k < CH_PER_WAVE; ++k) {
                // dword offsets {0,1,14,15} -> compiler merges to 2x ds_read2_b32
                const float f00 = lp[0];
                const float f01 = lp[1];
                const float f10 = lp[HW];
                const float f11 = lp[HW + 1];
                op[49 * k] = f00 * w00 + f01 * w01 + f10 * w10 + f11 * w11;
                lp += PLANE;
            }
        }
    }
}

extern "C" void kernel_launch(void* const* d_in, const int* in_sizes, int n_in,
                              void* d_out, int out_size, void* d_ws, size_t ws_size,
                              hipStream_t stream) {
    const float* feat = (const float*)d_in[0];
    const float* HBox = (const float*)d_in[1];
    const float* OBox = (const float*)d_in[2];
    const int* im_h = (const int*)d_in[3];
    const int* im_w = (const int*)d_in[4];
    float* out = (float*)d_out;

    // x: 72 roi slots + 1 geometry column; y: 32 channel groups.
    // Roi slots on the fast axis so the resident block set covers the full
    // 14.4-MB write band at each sweep step.
    dim3 grid(NSLOT + 1, 32);
    roi_align_kernel<<<grid, 256, 0, stream>>>(feat, HBox, OBox, im_h, im_w, out);
}